// Round 8
// baseline (322.273 us; speedup 1.0000x reference)
//
#include <hip/hip_runtime.h>
#include <hip/hip_bf16.h>

#define NB 4
#define NC 256
#define NHW 4096
#define CPG 8
#define GEPS 1e-6f

typedef __hip_bfloat16 bf16;
typedef __attribute__((ext_vector_type(8))) short bf16x8;
typedef __attribute__((ext_vector_type(4))) float f32x4;
typedef __attribute__((ext_vector_type(8))) unsigned short u16x8;

#define MFMA16(A,B,C) __builtin_amdgcn_mfma_f32_16x16x32_bf16(A,B,C,0,0,0)

typedef __attribute__((address_space(1))) const unsigned int as1_uint;
typedef __attribute__((address_space(3))) unsigned int as3_uint;
__device__ __forceinline__ void gload_lds16(const void* g, void* l){
  __builtin_amdgcn_global_load_lds((as1_uint*)g, (as3_uint*)l, 16, 0, 0);
}

__device__ __forceinline__ float u2f(unsigned short u){
  union { unsigned u32; float f; } w; w.u32 = ((unsigned)u) << 16; return w.f;
}
__device__ __forceinline__ bf16 f2b(float v){ return __float2bfloat16(v); }
__device__ __forceinline__ unsigned short f2bu(float v){
  union { bf16 h; unsigned short u; } w; w.h = __float2bfloat16(v); return w.u;
}

// ------- GroupNorm stats (blocks 0..127) + weight prep (blocks 128..1151) -------
__global__ __launch_bounds__(256)
void gn_stats_wprep_kernel(const float* __restrict__ x, float* __restrict__ stats,
                           const float* __restrict__ wq, const float* __restrict__ wk,
                           const float* __restrict__ wv, const float* __restrict__ wp,
                           const float* __restrict__ bq, const float* __restrict__ bk,
                           const float* __restrict__ bv,
                           bf16* __restrict__ wqkv, bf16* __restrict__ wpb,
                           float* __restrict__ bqs){
  if(blockIdx.x >= 128){
    int i = (blockIdx.x - 128) * 256 + threadIdx.x;     // 262144 threads
    if(i < 196608){
      float v;
      if(i < 65536)       v = wq[i] * 0.0625f;
      else if(i < 131072) v = wk[i - 65536];
      else                v = wv[i - 131072];
      wqkv[i] = f2b(v);
    } else {
      wpb[i - 196608] = f2b(wp[i - 196608]);
    }
    if(i < 768) bqs[i] = (i < 256) ? bq[i] * 0.0625f : (i < 512 ? bk[i - 256] : bv[i - 512]);
    return;
  }
  const int bg = blockIdx.x;
  const float* p = x + (size_t)bg * (CPG * NHW);
  float s = 0.f, s2 = 0.f;
  for(int i = threadIdx.x * 4; i < CPG * NHW; i += 1024){
    float4 v = *(const float4*)(p + i);
    s  += v.x + v.y + v.z + v.w;
    s2 += v.x*v.x + v.y*v.y + v.z*v.z + v.w*v.w;
  }
  __shared__ float red[256];
  red[threadIdx.x] = s; __syncthreads();
  for(int t = 128; t > 0; t >>= 1){
    if(threadIdx.x < t) red[threadIdx.x] += red[threadIdx.x + t];
    __syncthreads();
  }
  float sum = red[0]; __syncthreads();
  red[threadIdx.x] = s2; __syncthreads();
  for(int t = 128; t > 0; t >>= 1){
    if(threadIdx.x < t) red[threadIdx.x] += red[threadIdx.x + t];
    __syncthreads();
  }
  if(threadIdx.x == 0){
    const float inv_n = 1.f / (float)(CPG * NHW);
    float mean = sum * inv_n;
    float var = red[0] * inv_n - mean * mean;
    if(var < 0.f) var = 0.f;
    stats[bg * 2]     = mean;
    stats[bg * 2 + 1] = rsqrtf(var + GEPS);
  }
}

// ---------------- GN apply + transpose: xt[b][n][c] = GN(x)[b][c][n], bf16 ----------------
__global__ __launch_bounds__(256)
void gn_prep_kernel(const float* __restrict__ x, const float* __restrict__ stats,
                    const float* __restrict__ gsc, const float* __restrict__ gbi,
                    bf16* __restrict__ xt){
  const int b = blockIdx.z, cB = blockIdx.y * 64, nB = blockIdx.x * 64;
  __shared__ unsigned short Tt[64][80];
  const int tid = threadIdx.x;
  const float* xb = x + ((size_t)(b * NC + cB)) * NHW + nB;
  #pragma unroll
  for(int pass = 0; pass < 4; pass++){
    int c_loc = (tid >> 4) + pass * 16;
    int n0 = (tid & 15) * 4;
    float4 v = *(const float4*)(xb + (size_t)c_loc * NHW + n0);
    int c_abs = cB + c_loc, bg = b * 32 + (c_abs >> 3);
    float a = stats[bg * 2 + 1] * gsc[c_abs];
    float d = gbi[c_abs] - stats[bg * 2] * a;
    Tt[n0 + 0][c_loc] = f2bu(v.x * a + d);
    Tt[n0 + 1][c_loc] = f2bu(v.y * a + d);
    Tt[n0 + 2][c_loc] = f2bu(v.z * a + d);
    Tt[n0 + 3][c_loc] = f2bu(v.w * a + d);
  }
  __syncthreads();
  int n_loc = tid >> 2, cq = (tid & 3) * 16;
  u16x8 w0 = *(const u16x8*)&Tt[n_loc][cq];
  u16x8 w1 = *(const u16x8*)&Tt[n_loc][cq + 8];
  unsigned short* dst = (unsigned short*)xt + ((size_t)(b * NHW + nB + n_loc)) * NC + cB + cq;
  *(u16x8*)dst = w0;
  *(u16x8*)(dst + 8) = w1;
}

// ---------------- MFMA GEMM: D[o][n] = W[o][:]·Bm[n][:] + bias[o] ----------------
__global__ __launch_bounds__(256, 2)
void gemm_kernel(const bf16* __restrict__ Wb, const bf16* __restrict__ Bm,
                 const float* __restrict__ bias,
                 bf16* __restrict__ qo, bf16* __restrict__ ko, bf16* __restrict__ vo,
                 float* __restrict__ fo, const float* __restrict__ xres, int epi){
  const int nB = blockIdx.x * 128;
  const int oB = blockIdx.y * 128;
  const int tid = threadIdx.x;
  const int wave = tid >> 6, lane = tid & 63;
  const int l15 = lane & 15, quad = lane >> 4;
  const int wx = wave & 1, wy = wave >> 1;

  __shared__ __align__(16) unsigned short Ast[2][512 * 8];
  __shared__ __align__(16) unsigned short Bst[2][512 * 8];
  __shared__ __align__(16) unsigned short Tt[128 * 136];

  const short* Wp = (const short*)Wb;
  const short* Bp = (const short*)Bm;

  f32x4 acc[4][4];
  #pragma unroll
  for(int mi = 0; mi < 4; mi++)
    #pragma unroll
    for(int ni = 0; ni < 4; ni++) acc[mi][ni] = (f32x4){0.f, 0.f, 0.f, 0.f};

  #pragma unroll
  for(int t = 0; t < 2; t++){
    int qn0 = (wave * 2 + t) * 64, qn = qn0 + lane;
    int o = qn >> 2, slot = qn & 3;
    gload_lds16(Wp + (size_t)(oB + o) * NC + ((slot ^ (o & 3)) * 8), &Ast[0][qn0 * 8]);
  }
  #pragma unroll
  for(int t = 0; t < 2; t++){
    int qn0 = (wave * 2 + t) * 64, qn = qn0 + lane;
    int n = qn >> 2, slot = qn & 3;
    gload_lds16(Bp + (size_t)(nB + n) * NC + ((slot ^ (n & 3)) * 8), &Bst[0][qn0 * 8]);
  }

  for(int kt = 0; kt < 8; kt++){
    __syncthreads();
    const int p = kt & 1;
    if(kt < 7){
      const int k0 = (kt + 1) * 32;
      #pragma unroll
      for(int t = 0; t < 2; t++){
        int qn0 = (wave * 2 + t) * 64, qn = qn0 + lane;
        int o = qn >> 2, slot = qn & 3;
        gload_lds16(Wp + (size_t)(oB + o) * NC + k0 + ((slot ^ (o & 3)) * 8), &Ast[p ^ 1][qn0 * 8]);
      }
      #pragma unroll
      for(int t = 0; t < 2; t++){
        int qn0 = (wave * 2 + t) * 64, qn = qn0 + lane;
        int n = qn >> 2, slot = qn & 3;
        gload_lds16(Bp + (size_t)(nB + n) * NC + k0 + ((slot ^ (n & 3)) * 8), &Bst[p ^ 1][qn0 * 8]);
      }
    }
    bf16x8 Af[4], Bf[4];
    #pragma unroll
    for(int mi = 0; mi < 4; mi++){
      int o = wx * 64 + mi * 16 + l15;
      Af[mi] = *(const bf16x8*)&Ast[p][(o * 4 + (quad ^ (o & 3))) * 8];
    }
    #pragma unroll
    for(int ni = 0; ni < 4; ni++){
      int n = wy * 64 + ni * 16 + l15;
      Bf[ni] = *(const bf16x8*)&Bst[p][(n * 4 + (quad ^ (n & 3))) * 8];
    }
    #pragma unroll
    for(int mi = 0; mi < 4; mi++)
      #pragma unroll
      for(int ni = 0; ni < 4; ni++)
        acc[mi][ni] = MFMA16(Af[mi], Bf[ni], acc[mi][ni]);
  }

  float bi[4][4];
  #pragma unroll
  for(int mi = 0; mi < 4; mi++)
    #pragma unroll
    for(int r = 0; r < 4; r++)
      bi[mi][r] = bias[oB + wx * 64 + mi * 16 + quad * 4 + r];

  if(epi == 1){
    #pragma unroll
    for(int mi = 0; mi < 4; mi++){
      #pragma unroll
      for(int ni = 0; ni < 4; ni++){
        int na = nB + wy * 64 + ni * 16 + l15;
        #pragma unroll
        for(int r = 0; r < 4; r++){
          int c = oB + wx * 64 + mi * 16 + quad * 4 + r;
          size_t idx = ((size_t)(na >> 12) * NC + c) * NHW + (na & 4095);
          fo[idx] = acc[mi][ni][r] + bi[mi][r] + xres[idx];
        }
      }
    }
  } else if(oB >= 512){
    #pragma unroll
    for(int mi = 0; mi < 4; mi++){
      #pragma unroll
      for(int ni = 0; ni < 4; ni++){
        int na = nB + wy * 64 + ni * 16 + l15;
        #pragma unroll
        for(int r = 0; r < 4; r++){
          int c = oB - 512 + wx * 64 + mi * 16 + quad * 4 + r;
          vo[((size_t)(na >> 12) * NC + c) * NHW + (na & 4095)] = f2b(acc[mi][ni][r] + bi[mi][r]);
        }
      }
    }
  } else {
    #pragma unroll
    for(int mi = 0; mi < 4; mi++){
      int ob = wx * 64 + mi * 16 + quad * 4;
      #pragma unroll
      for(int ni = 0; ni < 4; ni++){
        int nl = wy * 64 + ni * 16 + l15;
        ushort4 pk;
        pk.x = f2bu(acc[mi][ni][0] + bi[mi][0]);
        pk.y = f2bu(acc[mi][ni][1] + bi[mi][1]);
        pk.z = f2bu(acc[mi][ni][2] + bi[mi][2]);
        pk.w = f2bu(acc[mi][ni][3] + bi[mi][3]);
        *(ushort4*)&Tt[nl * 136 + ob] = pk;
      }
    }
    __syncthreads();
    bf16* dst = (oB < 256) ? qo : ko;
    const int oc0 = oB & 255;
    int row = tid >> 1, half = tid & 1;
    unsigned short* gp = (unsigned short*)dst + (size_t)(nB + row) * NC + oc0 + half * 64;
    #pragma unroll
    for(int j = 0; j < 8; j++){
      u16x8 w = *(const u16x8*)&Tt[row * 136 + half * 64 + j * 8];
      *(u16x8*)(gp + j * 8) = w;
    }
  }
}

// ---------------- MFMA flash v5: K direct-global, V LDS dbuf, no-max softmax ----------------
// q,kt: [B][n][C] (q pre-scaled 1/16)  v: [B][C][n]
__global__ __launch_bounds__(256, 2)
void flash_mfma5_kernel(const bf16* __restrict__ qg, const bf16* __restrict__ ktg,
                        const bf16* __restrict__ vg, bf16* __restrict__ Opart,
                        float* __restrict__ lpart){
  const int b = blockIdx.y, h = blockIdx.z;
  const int i0 = blockIdx.x * 128;
  const int tid = threadIdx.x;
  const int wave = tid >> 6, lane = tid & 63;
  const int l15 = lane & 15, quad = lane >> 4;

  __shared__ __align__(16) unsigned short Vt[2][1024 * 8];    // 2 x 16 KB
  __shared__ __align__(16) unsigned short Pt_all[4][32 * 40]; // 10 KB
  unsigned short* Pt = Pt_all[wave];

  bf16x8 Qf[2][8];
  #pragma unroll
  for(int ist = 0; ist < 2; ist++){
    const short* qp = (const short*)qg +
        ((size_t)b * NHW + i0 + wave * 32 + ist * 16 + l15) * NC + quad * 8;
    #pragma unroll
    for(int ks = 0; ks < 8; ks++) Qf[ist][ks] = *(const bf16x8*)(qp + ks * 32);
  }

  const short* kb = (const short*)ktg + ((size_t)b * NHW + h * 1024) * NC;
  const short* vb = (const short*)vg + (size_t)b * NC * NHW + h * 1024;

  f32x4 O[2][16];
  #pragma unroll
  for(int ist = 0; ist < 2; ist++)
    #pragma unroll
    for(int ct = 0; ct < 16; ct++) O[ist][ct] = (f32x4){0.f, 0.f, 0.f, 0.f};
  float lr0 = 0.f, lr1 = 0.f;

  // prologue: stage V tile 0
  #pragma unroll
  for(int t = 0; t < 4; t++){
    int qn0 = (wave * 4 + t) * 64, qn = qn0 + lane;
    int c = qn >> 2, slot = qn & 3, gc = slot ^ ((c >> 1) & 3);
    gload_lds16(vb + (size_t)c * NHW + gc * 8, &Vt[0][qn0 * 8]);
  }

  for(int jt = 0; jt < 32; jt++){
    __syncthreads();                        // V(jt) staged; V(jt-1) reads done
    const int p = jt & 1;
    if(jt < 31){
      const int j0n = (jt + 1) * 32;
      #pragma unroll
      for(int t = 0; t < 4; t++){
        int qn0 = (wave * 4 + t) * 64, qn = qn0 + lane;
        int c = qn >> 2, slot = qn & 3, gc = slot ^ ((c >> 1) & 3);
        gload_lds16(vb + (size_t)c * NHW + j0n + gc * 8, &Vt[p ^ 1][qn0 * 8]);
      }
    }
    const int j0 = jt * 32;
    // ---- S^T = K·Q^T, K fragments straight from global (L1/L2-served) ----
    f32x4 S[2][2];
    #pragma unroll
    for(int st = 0; st < 2; st++){
      S[st][0] = (f32x4){0.f, 0.f, 0.f, 0.f};
      S[st][1] = (f32x4){0.f, 0.f, 0.f, 0.f};
      const short* kp = kb + (size_t)(j0 + st * 16 + l15) * NC + quad * 8;
      #pragma unroll
      for(int ks = 0; ks < 8; ks++){
        bf16x8 kf = *(const bf16x8*)(kp + ks * 32);
        S[st][0] = MFMA16(kf, Qf[0][ks], S[st][0]);
        S[st][1] = MFMA16(kf, Qf[1][ks], S[st][1]);
      }
    }
    // ---- P = exp(S), row-sum partials, store A-layout ----
    #pragma unroll
    for(int ist = 0; ist < 2; ist++){
      #pragma unroll
      for(int st = 0; st < 2; st++){
        f32x4 sv = S[st][ist];
        float p0 = __expf(sv[0]), p1 = __expf(sv[1]);
        float p2 = __expf(sv[2]), p3 = __expf(sv[3]);
        if(ist == 0) lr0 += (p0 + p1) + (p2 + p3);
        else         lr1 += (p0 + p1) + (p2 + p3);
        ushort4 pk; pk.x = f2bu(p0); pk.y = f2bu(p1); pk.z = f2bu(p2); pk.w = f2bu(p3);
        *(ushort4*)&Pt[(ist * 16 + l15) * 40 + st * 16 + quad * 4] = pk;
      }
    }
    // ---- O += P·V^T from LDS ----
    bf16x8 Pf0 = *(const bf16x8*)&Pt[(l15) * 40 + quad * 8];
    bf16x8 Pf1 = *(const bf16x8*)&Pt[(16 + l15) * 40 + quad * 8];
    #pragma unroll
    for(int ct = 0; ct < 16; ct++){
      int c = ct * 16 + l15;
      int slot = quad ^ ((c >> 1) & 3);
      bf16x8 vf = *(const bf16x8*)&Vt[p][(c * 4 + slot) * 8];
      O[0][ct] = MFMA16(Pf0, vf, O[0][ct]);
      O[1][ct] = MFMA16(Pf1, vf, O[1][ct]);
    }
  }

  lr0 += __shfl_xor(lr0, 16); lr0 += __shfl_xor(lr0, 32);
  lr1 += __shfl_xor(lr1, 16); lr1 += __shfl_xor(lr1, 32);

  __syncthreads();                          // all PV reads of Vt done; reuse as scratch
  // ---- coalesced Opart store via LDS scratch (per-wave 8 KB region) ----
  unsigned short* Vs = &Vt[0][0] + wave * 4096;
  const size_t hb = (size_t)(h * NB + b) * NHW;
  #pragma unroll
  for(int ist = 0; ist < 2; ist++){
    #pragma unroll
    for(int r = 0; r < 4; r++)
      #pragma unroll
      for(int ct = 0; ct < 16; ct++)
        Vs[(quad * 4 + r) * 256 + ct * 16 + l15] = f2bu(O[ist][ct][r]);
    int row = lane >> 2, c0 = (lane & 3) * 64;
    unsigned short* gp = (unsigned short*)Opart +
        (hb + i0 + wave * 32 + ist * 16 + row) * NC + c0;
    #pragma unroll
    for(int t = 0; t < 8; t++){
      u16x8 w = *(const u16x8*)&Vs[row * 256 + c0 + t * 8];
      *(u16x8*)(gp + t * 8) = w;
    }
  }
  if(lane < 32){
    float lv = (lane < 16) ? lr0 : lr1;
    lpart[hb + i0 + wave * 32 + lane] = lv;
  }
}

// ---------------- combine the 4 j-quarters ----------------
__global__ __launch_bounds__(256)
void flash_combine4_kernel(const bf16* __restrict__ Opart, const float* __restrict__ lpart,
                           bf16* __restrict__ attn){
  int t = blockIdx.x * 256 + threadIdx.x;
  int ng = t >> 3;
  int c0 = (t & 7) * 32;
  const int HS = NB * NHW;
  float l = lpart[ng] + lpart[HS + ng] + lpart[2 * HS + ng] + lpart[3 * HS + ng];
  float inv = 1.f / l;
  const unsigned short* O0 = (const unsigned short*)Opart + (size_t)ng * NC + c0;
  unsigned short* dst = (unsigned short*)attn + (size_t)ng * NC + c0;
  #pragma unroll
  for(int u = 0; u < 32; u += 8){
    u16x8 a0 = *(const u16x8*)(O0 + u);
    u16x8 a1 = *(const u16x8*)(O0 + (size_t)HS * NC + u);
    u16x8 a2 = *(const u16x8*)(O0 + (size_t)2 * HS * NC + u);
    u16x8 a3 = *(const u16x8*)(O0 + (size_t)3 * HS * NC + u);
    u16x8 o;
    #pragma unroll
    for(int e = 0; e < 8; e++)
      o[e] = f2bu((u2f(a0[e]) + u2f(a1[e]) + u2f(a2[e]) + u2f(a3[e])) * inv);
    *(u16x8*)(dst + u) = o;
  }
}

extern "C" void kernel_launch(void* const* d_in, const int* in_sizes, int n_in,
                              void* d_out, int out_size, void* d_ws, size_t ws_size,
                              hipStream_t stream){
  (void)in_sizes; (void)n_in; (void)out_size; (void)ws_size;
  const float* x        = (const float*)d_in[0];
  const float* gn_scale = (const float*)d_in[1];
  const float* gn_bias  = (const float*)d_in[2];
  const float* wq = (const float*)d_in[3];  const float* bq = (const float*)d_in[4];
  const float* wk = (const float*)d_in[5];  const float* bk = (const float*)d_in[6];
  const float* wv = (const float*)d_in[7];  const float* bv = (const float*)d_in[8];
  const float* wp = (const float*)d_in[9];  const float* bp = (const float*)d_in[10];
  float* out = (float*)d_out;

  char* ws = (char*)d_ws;
  const size_t MB = 1048576;
  float* stats = (float*)ws;
  float* bqs   = (float*)(ws + 4096);
  bf16* wqkv   = (bf16*)(ws + 8192);
  bf16* wpb    = (bf16*)(ws + 8192 + 393216);
  bf16* xt     = (bf16*)(ws + 1 * MB);
  bf16* Opart  = xt;                                 // alias: xt dead after qkv gemm
  bf16* q      = (bf16*)(ws + 33 * MB);
  bf16* k      = (bf16*)(ws + 41 * MB);
  bf16* v      = (bf16*)(ws + 49 * MB);
  float* lpart = (float*)(ws + 57 * MB);
  bf16* attn   = q;                                  // alias: q dead after flash

  gn_stats_wprep_kernel<<<1152, 256, 0, stream>>>(
      x, stats, wq, wk, wv, wp, bq, bk, bv, wqkv, wpb, bqs);
  gn_prep_kernel<<<dim3(64, 4, NB), 256, 0, stream>>>(x, stats, gn_scale, gn_bias, xt);

  gemm_kernel<<<dim3(128, 6), 256, 0, stream>>>(
      wqkv, xt, bqs, q, k, v, nullptr, nullptr, 0);

  flash_mfma5_kernel<<<dim3(32, NB, 4), 256, 0, stream>>>(q, k, v, Opart, lpart);
  flash_combine4_kernel<<<512, 256, 0, stream>>>(Opart, lpart, attn);

  gemm_kernel<<<dim3(128, 2), 256, 0, stream>>>(
      wpb, attn, bp, nullptr, nullptr, nullptr, out, x, 1);
}

// Round 9
// 232.936 us; speedup vs baseline: 1.3835x; 1.3835x over previous
//
#include <hip/hip_runtime.h>
#include <hip/hip_bf16.h>

#define NB 4
#define NC 256
#define NHW 4096
#define CPG 8
#define GEPS 1e-6f

typedef __hip_bfloat16 bf16;
typedef __attribute__((ext_vector_type(8))) short bf16x8;
typedef __attribute__((ext_vector_type(4))) float f32x4;
typedef __attribute__((ext_vector_type(8))) unsigned short u16x8;

#define MFMA16(A,B,C) __builtin_amdgcn_mfma_f32_16x16x32_bf16(A,B,C,0,0,0)

typedef __attribute__((address_space(1))) const unsigned int as1_uint;
typedef __attribute__((address_space(3))) unsigned int as3_uint;
__device__ __forceinline__ void gload_lds16(const void* g, void* l){
  __builtin_amdgcn_global_load_lds((as1_uint*)g, (as3_uint*)l, 16, 0, 0);
}

__device__ __forceinline__ float u2f(unsigned short u){
  union { unsigned u32; float f; } w; w.u32 = ((unsigned)u) << 16; return w.f;
}
__device__ __forceinline__ bf16 f2b(float v){ return __float2bfloat16(v); }
__device__ __forceinline__ unsigned short f2bu(float v){
  union { bf16 h; unsigned short u; } w; w.h = __float2bfloat16(v); return w.u;
}

// ------- GroupNorm stats (blocks 0..127) + weight prep (blocks 128..1151) -------
__global__ __launch_bounds__(256)
void gn_stats_wprep_kernel(const float* __restrict__ x, float* __restrict__ stats,
                           const float* __restrict__ wq, const float* __restrict__ wk,
                           const float* __restrict__ wv, const float* __restrict__ wp,
                           const float* __restrict__ bq, const float* __restrict__ bk,
                           const float* __restrict__ bv,
                           bf16* __restrict__ wqkv, bf16* __restrict__ wpb,
                           float* __restrict__ bqs){
  if(blockIdx.x >= 128){
    int i = (blockIdx.x - 128) * 256 + threadIdx.x;
    if(i < 196608){
      float v;
      if(i < 65536)       v = wq[i] * 0.0625f;
      else if(i < 131072) v = wk[i - 65536];
      else                v = wv[i - 131072];
      wqkv[i] = f2b(v);
    } else {
      wpb[i - 196608] = f2b(wp[i - 196608]);
    }
    if(i < 768) bqs[i] = (i < 256) ? bq[i] * 0.0625f : (i < 512 ? bk[i - 256] : bv[i - 512]);
    return;
  }
  const int bg = blockIdx.x;
  const float* p = x + (size_t)bg * (CPG * NHW);
  float s = 0.f, s2 = 0.f;
  for(int i = threadIdx.x * 4; i < CPG * NHW; i += 1024){
    float4 v = *(const float4*)(p + i);
    s  += v.x + v.y + v.z + v.w;
    s2 += v.x*v.x + v.y*v.y + v.z*v.z + v.w*v.w;
  }
  __shared__ float red[256];
  red[threadIdx.x] = s; __syncthreads();
  for(int t = 128; t > 0; t >>= 1){
    if(threadIdx.x < t) red[threadIdx.x] += red[threadIdx.x + t];
    __syncthreads();
  }
  float sum = red[0]; __syncthreads();
  red[threadIdx.x] = s2; __syncthreads();
  for(int t = 128; t > 0; t >>= 1){
    if(threadIdx.x < t) red[threadIdx.x] += red[threadIdx.x + t];
    __syncthreads();
  }
  if(threadIdx.x == 0){
    const float inv_n = 1.f / (float)(CPG * NHW);
    float mean = sum * inv_n;
    float var = red[0] * inv_n - mean * mean;
    if(var < 0.f) var = 0.f;
    stats[bg * 2]     = mean;
    stats[bg * 2 + 1] = rsqrtf(var + GEPS);
  }
}

// ---------------- GN apply + transpose: xt[b][n][c] = GN(x)[b][c][n], bf16 ----------------
__global__ __launch_bounds__(256)
void gn_prep_kernel(const float* __restrict__ x, const float* __restrict__ stats,
                    const float* __restrict__ gsc, const float* __restrict__ gbi,
                    bf16* __restrict__ xt){
  const int b = blockIdx.z, cB = blockIdx.y * 64, nB = blockIdx.x * 64;
  __shared__ unsigned short Tt[64][80];
  const int tid = threadIdx.x;
  const float* xb = x + ((size_t)(b * NC + cB)) * NHW + nB;
  #pragma unroll
  for(int pass = 0; pass < 4; pass++){
    int c_loc = (tid >> 4) + pass * 16;
    int n0 = (tid & 15) * 4;
    float4 v = *(const float4*)(xb + (size_t)c_loc * NHW + n0);
    int c_abs = cB + c_loc, bg = b * 32 + (c_abs >> 3);
    float a = stats[bg * 2 + 1] * gsc[c_abs];
    float d = gbi[c_abs] - stats[bg * 2] * a;
    Tt[n0 + 0][c_loc] = f2bu(v.x * a + d);
    Tt[n0 + 1][c_loc] = f2bu(v.y * a + d);
    Tt[n0 + 2][c_loc] = f2bu(v.z * a + d);
    Tt[n0 + 3][c_loc] = f2bu(v.w * a + d);
  }
  __syncthreads();
  int n_loc = tid >> 2, cq = (tid & 3) * 16;
  u16x8 w0 = *(const u16x8*)&Tt[n_loc][cq];
  u16x8 w1 = *(const u16x8*)&Tt[n_loc][cq + 8];
  unsigned short* dst = (unsigned short*)xt + ((size_t)(b * NHW + nB + n_loc)) * NC + cB + cq;
  *(u16x8*)dst = w0;
  *(u16x8*)(dst + 8) = w1;
}

// ---------------- MFMA GEMM: D[o][n] = W[o][:]·Bm[n][:] + bias[o] ----------------
__global__ __launch_bounds__(256, 2)
void gemm_kernel(const bf16* __restrict__ Wb, const bf16* __restrict__ Bm,
                 const float* __restrict__ bias,
                 bf16* __restrict__ qo, bf16* __restrict__ ko, bf16* __restrict__ vo,
                 float* __restrict__ fo, const float* __restrict__ xres, int epi){
  const int nB = blockIdx.x * 128;
  const int oB = blockIdx.y * 128;
  const int tid = threadIdx.x;
  const int wave = tid >> 6, lane = tid & 63;
  const int l15 = lane & 15, quad = lane >> 4;
  const int wx = wave & 1, wy = wave >> 1;

  __shared__ __align__(16) unsigned short Ast[2][512 * 8];
  __shared__ __align__(16) unsigned short Bst[2][512 * 8];
  __shared__ __align__(16) unsigned short Tt[128 * 136];   // also fp32 scratch for epi=1

  const short* Wp = (const short*)Wb;
  const short* Bp = (const short*)Bm;

  f32x4 acc[4][4];
  #pragma unroll
  for(int mi = 0; mi < 4; mi++)
    #pragma unroll
    for(int ni = 0; ni < 4; ni++) acc[mi][ni] = (f32x4){0.f, 0.f, 0.f, 0.f};

  #pragma unroll
  for(int t = 0; t < 2; t++){
    int qn0 = (wave * 2 + t) * 64, qn = qn0 + lane;
    int o = qn >> 2, slot = qn & 3;
    gload_lds16(Wp + (size_t)(oB + o) * NC + ((slot ^ (o & 3)) * 8), &Ast[0][qn0 * 8]);
  }
  #pragma unroll
  for(int t = 0; t < 2; t++){
    int qn0 = (wave * 2 + t) * 64, qn = qn0 + lane;
    int n = qn >> 2, slot = qn & 3;
    gload_lds16(Bp + (size_t)(nB + n) * NC + ((slot ^ (n & 3)) * 8), &Bst[0][qn0 * 8]);
  }

  for(int kt = 0; kt < 8; kt++){
    __syncthreads();
    const int p = kt & 1;
    if(kt < 7){
      const int k0 = (kt + 1) * 32;
      #pragma unroll
      for(int t = 0; t < 2; t++){
        int qn0 = (wave * 2 + t) * 64, qn = qn0 + lane;
        int o = qn >> 2, slot = qn & 3;
        gload_lds16(Wp + (size_t)(oB + o) * NC + k0 + ((slot ^ (o & 3)) * 8), &Ast[p ^ 1][qn0 * 8]);
      }
      #pragma unroll
      for(int t = 0; t < 2; t++){
        int qn0 = (wave * 2 + t) * 64, qn = qn0 + lane;
        int n = qn >> 2, slot = qn & 3;
        gload_lds16(Bp + (size_t)(nB + n) * NC + k0 + ((slot ^ (n & 3)) * 8), &Bst[p ^ 1][qn0 * 8]);
      }
    }
    bf16x8 Af[4], Bf[4];
    #pragma unroll
    for(int mi = 0; mi < 4; mi++){
      int o = wx * 64 + mi * 16 + l15;
      Af[mi] = *(const bf16x8*)&Ast[p][(o * 4 + (quad ^ (o & 3))) * 8];
    }
    #pragma unroll
    for(int ni = 0; ni < 4; ni++){
      int n = wy * 64 + ni * 16 + l15;
      Bf[ni] = *(const bf16x8*)&Bst[p][(n * 4 + (quad ^ (n & 3))) * 8];
    }
    #pragma unroll
    for(int mi = 0; mi < 4; mi++)
      #pragma unroll
      for(int ni = 0; ni < 4; ni++)
        acc[mi][ni] = MFMA16(Af[mi], Bf[ni], acc[mi][ni]);
  }

  float bi[4][4];
  #pragma unroll
  for(int mi = 0; mi < 4; mi++)
    #pragma unroll
    for(int r = 0; r < 4; r++)
      bi[mi][r] = bias[oB + wx * 64 + mi * 16 + quad * 4 + r];

  if(epi == 1){
    // proj: fp32 out [b][c][n] + residual, transposed via LDS for coalesced I/O
    float* Ts = (float*)Tt;                 // 32 x 132 fp32 = 16.9 KB
    #pragma unroll
    for(int mi = 0; mi < 4; mi++){
      __syncthreads();
      #pragma unroll
      for(int ni = 0; ni < 4; ni++)
        #pragma unroll
        for(int r = 0; r < 4; r++)
          Ts[(wx * 16 + quad * 4 + r) * 132 + wy * 64 + ni * 16 + l15] =
              acc[mi][ni][r] + bi[mi][r];
      __syncthreads();
      int row = tid >> 3;                    // 0..31
      int col0 = (tid & 7) * 16;
      int c = oB + (row >> 4) * 64 + mi * 16 + (row & 15);
      size_t gb = ((size_t)((nB >> 12) * NC + c)) * NHW + (nB & 4095) + col0;
      #pragma unroll
      for(int t = 0; t < 4; t++){
        float4 vv = *(const float4*)&Ts[row * 132 + col0 + t * 4];
        float4 rr = *(const float4*)(xres + gb + t * 4);
        vv.x += rr.x; vv.y += rr.y; vv.z += rr.z; vv.w += rr.w;
        *(float4*)(fo + gb + t * 4) = vv;
      }
    }
  } else if(oB >= 512){
    // v: bf16 out [b][c][n], transposed via Tt for coalesced stores
    #pragma unroll
    for(int mi = 0; mi < 4; mi++)
      #pragma unroll
      for(int ni = 0; ni < 4; ni++)
        #pragma unroll
        for(int r = 0; r < 4; r++)
          Tt[(wx * 64 + mi * 16 + quad * 4 + r) * 136 + wy * 64 + ni * 16 + l15] =
              f2bu(acc[mi][ni][r] + bi[mi][r]);
    __syncthreads();
    int row = tid >> 1, half = tid & 1;
    int c = oB - 512 + row;
    unsigned short* gp = (unsigned short*)vo +
        ((size_t)((nB >> 12) * NC + c)) * NHW + (nB & 4095) + half * 64;
    #pragma unroll
    for(int j = 0; j < 8; j++){
      u16x8 w = *(const u16x8*)&Tt[row * 136 + half * 64 + j * 8];
      *(u16x8*)(gp + j * 8) = w;
    }
  } else {
    // q/k: transpose through LDS, write [n][C]
    #pragma unroll
    for(int mi = 0; mi < 4; mi++){
      int ob = wx * 64 + mi * 16 + quad * 4;
      #pragma unroll
      for(int ni = 0; ni < 4; ni++){
        int nl = wy * 64 + ni * 16 + l15;
        ushort4 pk;
        pk.x = f2bu(acc[mi][ni][0] + bi[mi][0]);
        pk.y = f2bu(acc[mi][ni][1] + bi[mi][1]);
        pk.z = f2bu(acc[mi][ni][2] + bi[mi][2]);
        pk.w = f2bu(acc[mi][ni][3] + bi[mi][3]);
        *(ushort4*)&Tt[nl * 136 + ob] = pk;
      }
    }
    __syncthreads();
    bf16* dst = (oB < 256) ? qo : ko;
    const int oc0 = oB & 255;
    int row = tid >> 1, half = tid & 1;
    unsigned short* gp = (unsigned short*)dst + (size_t)(nB + row) * NC + oc0 + half * 64;
    #pragma unroll
    for(int j = 0; j < 8; j++){
      u16x8 w = *(const u16x8*)&Tt[row * 136 + half * 64 + j * 8];
      *(u16x8*)(gp + j * 8) = w;
    }
  }
}

// ---------------- MFMA flash v6: K+V LDS dbuf, conflict-free swizzles ----------------
// q,kt: [B][n][C] (q pre-scaled 1/16)  v: [B][C][n]
__global__ __launch_bounds__(256, 2)
void flash_mfma6_kernel(const bf16* __restrict__ qg, const bf16* __restrict__ ktg,
                        const bf16* __restrict__ vg, bf16* __restrict__ Opart,
                        float* __restrict__ lpart){
  const int b = blockIdx.y, h = blockIdx.z;
  const int i0 = blockIdx.x * 128;
  const int tid = threadIdx.x;
  const int wave = tid >> 6, lane = tid & 63;
  const int l15 = lane & 15, quad = lane >> 4;

  __shared__ __align__(16) unsigned short KV[4][8192];        // K0,K1,V0,V1 (64 KB)
  __shared__ __align__(16) unsigned short Pt_all[4][32 * 40]; // 10 KB
  unsigned short* Pt = Pt_all[wave];

  bf16x8 Qf[2][8];
  #pragma unroll
  for(int ist = 0; ist < 2; ist++){
    const short* qp = (const short*)qg +
        ((size_t)b * NHW + i0 + wave * 32 + ist * 16 + l15) * NC + quad * 8;
    #pragma unroll
    for(int ks = 0; ks < 8; ks++) Qf[ist][ks] = *(const bf16x8*)(qp + ks * 32);
  }

  const short* kb = (const short*)ktg + ((size_t)b * NHW + h * 1024) * NC;
  const short* vb = (const short*)vg + (size_t)b * NC * NHW + h * 1024;

  f32x4 O[2][16];
  #pragma unroll
  for(int ist = 0; ist < 2; ist++)
    #pragma unroll
    for(int ct = 0; ct < 16; ct++) O[ist][ct] = (f32x4){0.f, 0.f, 0.f, 0.f};
  float lr0 = 0.f, lr1 = 0.f;

  // prologue: stage K(0), V(0)
  #pragma unroll
  for(int t = 0; t < 4; t++){
    int qn0 = (wave * 4 + t) * 64, qn = qn0 + lane;
    int j = qn >> 5, slot = qn & 31;
    gload_lds16(kb + (size_t)j * NC + ((slot ^ (j & 7)) * 8), &KV[0][qn0 * 8]);
  }
  #pragma unroll
  for(int t = 0; t < 4; t++){
    int qn0 = (wave * 4 + t) * 64, qn = qn0 + lane;
    int c = qn >> 2, slot = qn & 3;
    gload_lds16(vb + (size_t)c * NHW + ((slot ^ ((c >> 1) & 3)) * 8), &KV[2][qn0 * 8]);
  }

  for(int jt = 0; jt < 32; jt++){
    __syncthreads();                        // tiles(jt) staged; tiles(jt-1) reads done
    const int p = jt & 1;
    if(jt < 31){
      const int j0n = (jt + 1) * 32;
      #pragma unroll
      for(int t = 0; t < 4; t++){
        int qn0 = (wave * 4 + t) * 64, qn = qn0 + lane;
        int j = qn >> 5, slot = qn & 31;
        gload_lds16(kb + (size_t)(j0n + j) * NC + ((slot ^ (j & 7)) * 8), &KV[p ^ 1][qn0 * 8]);
      }
      #pragma unroll
      for(int t = 0; t < 4; t++){
        int qn0 = (wave * 4 + t) * 64, qn = qn0 + lane;
        int c = qn >> 2, slot = qn & 3;
        gload_lds16(vb + (size_t)c * NHW + j0n + ((slot ^ ((c >> 1) & 3)) * 8),
                    &KV[2 + (p ^ 1)][qn0 * 8]);
      }
    }
    // ---- S^T = K·Q^T from LDS (K-frag read once, both i-subtiles) ----
    f32x4 S[2][2];
    #pragma unroll
    for(int st = 0; st < 2; st++){
      S[st][0] = (f32x4){0.f, 0.f, 0.f, 0.f};
      S[st][1] = (f32x4){0.f, 0.f, 0.f, 0.f};
      const int j = st * 16 + l15;
      const unsigned short* kr = &KV[p][(size_t)j * 256];
      #pragma unroll
      for(int ks = 0; ks < 8; ks++){
        int slot = (ks * 4 + quad) ^ (j & 7);
        bf16x8 kf = *(const bf16x8*)&kr[slot * 8];
        S[st][0] = MFMA16(kf, Qf[0][ks], S[st][0]);
        S[st][1] = MFMA16(kf, Qf[1][ks], S[st][1]);
      }
    }
    // ---- P = exp(S), row-sum partials, store A-layout ----
    #pragma unroll
    for(int ist = 0; ist < 2; ist++){
      #pragma unroll
      for(int st = 0; st < 2; st++){
        f32x4 sv = S[st][ist];
        float p0 = __expf(sv[0]), p1 = __expf(sv[1]);
        float p2 = __expf(sv[2]), p3 = __expf(sv[3]);
        if(ist == 0) lr0 += (p0 + p1) + (p2 + p3);
        else         lr1 += (p0 + p1) + (p2 + p3);
        ushort4 pk; pk.x = f2bu(p0); pk.y = f2bu(p1); pk.z = f2bu(p2); pk.w = f2bu(p3);
        *(ushort4*)&Pt[(ist * 16 + l15) * 40 + st * 16 + quad * 4] = pk;
      }
    }
    // ---- O += P·V^T from LDS (V-frag read once, both i-subtiles) ----
    bf16x8 Pf0 = *(const bf16x8*)&Pt[(l15) * 40 + quad * 8];
    bf16x8 Pf1 = *(const bf16x8*)&Pt[(16 + l15) * 40 + quad * 8];
    #pragma unroll
    for(int ct = 0; ct < 16; ct++){
      int c = ct * 16 + l15;
      int slot = quad ^ ((c >> 1) & 3);
      bf16x8 vf = *(const bf16x8*)&KV[2 + p][(c * 4 + slot) * 8];
      O[0][ct] = MFMA16(Pf0, vf, O[0][ct]);
      O[1][ct] = MFMA16(Pf1, vf, O[1][ct]);
    }
  }

  lr0 += __shfl_xor(lr0, 16); lr0 += __shfl_xor(lr0, 32);
  lr1 += __shfl_xor(lr1, 16); lr1 += __shfl_xor(lr1, 32);

  __syncthreads();                          // all tile reads done; reuse KV as scratch
  // ---- coalesced Opart store via per-wave LDS scratch (stride 264: bank-spread) ----
  unsigned short* Vs = &KV[0][0] + wave * 4224;     // 16 rows x 264
  const size_t hb = (size_t)(h * NB + b) * NHW;
  #pragma unroll
  for(int ist = 0; ist < 2; ist++){
    #pragma unroll
    for(int r = 0; r < 4; r++)
      #pragma unroll
      for(int ct = 0; ct < 16; ct++)
        Vs[(quad * 4 + r) * 264 + ct * 16 + l15] = f2bu(O[ist][ct][r]);
    int row = lane & 15, chunk = lane >> 4;
    unsigned short* gp = (unsigned short*)Opart +
        (hb + i0 + wave * 32 + ist * 16 + row) * NC + chunk * 64;
    #pragma unroll
    for(int t = 0; t < 8; t++){
      u16x8 w = *(const u16x8*)&Vs[row * 264 + chunk * 64 + t * 8];
      *(u16x8*)(gp + t * 8) = w;
    }
  }
  if(lane < 32){
    float lv = (lane < 16) ? lr0 : lr1;
    lpart[hb + i0 + wave * 32 + lane] = lv;
  }
}

// ---------------- combine the 4 j-quarters ----------------
__global__ __launch_bounds__(256)
void flash_combine4_kernel(const bf16* __restrict__ Opart, const float* __restrict__ lpart,
                           bf16* __restrict__ attn){
  int t = blockIdx.x * 256 + threadIdx.x;
  int ng = t >> 3;
  int c0 = (t & 7) * 32;
  const int HS = NB * NHW;
  float l = lpart[ng] + lpart[HS + ng] + lpart[2 * HS + ng] + lpart[3 * HS + ng];
  float inv = 1.f / l;
  const unsigned short* O0 = (const unsigned short*)Opart + (size_t)ng * NC + c0;
  unsigned short* dst = (unsigned short*)attn + (size_t)ng * NC + c0;
  #pragma unroll
  for(int u = 0; u < 32; u += 8){
    u16x8 a0 = *(const u16x8*)(O0 + u);
    u16x8 a1 = *(const u16x8*)(O0 + (size_t)HS * NC + u);
    u16x8 a2 = *(const u16x8*)(O0 + (size_t)2 * HS * NC + u);
    u16x8 a3 = *(const u16x8*)(O0 + (size_t)3 * HS * NC + u);
    u16x8 o;
    #pragma unroll
    for(int e = 0; e < 8; e++)
      o[e] = f2bu((u2f(a0[e]) + u2f(a1[e]) + u2f(a2[e]) + u2f(a3[e])) * inv);
    *(u16x8*)(dst + u) = o;
  }
}

extern "C" void kernel_launch(void* const* d_in, const int* in_sizes, int n_in,
                              void* d_out, int out_size, void* d_ws, size_t ws_size,
                              hipStream_t stream){
  (void)in_sizes; (void)n_in; (void)out_size; (void)ws_size;
  const float* x        = (const float*)d_in[0];
  const float* gn_scale = (const float*)d_in[1];
  const float* gn_bias  = (const float*)d_in[2];
  const float* wq = (const float*)d_in[3];  const float* bq = (const float*)d_in[4];
  const float* wk = (const float*)d_in[5];  const float* bk = (const float*)d_in[6];
  const float* wv = (const float*)d_in[7];  const float* bv = (const float*)d_in[8];
  const float* wp = (const float*)d_in[9];  const float* bp = (const float*)d_in[10];
  float* out = (float*)d_out;

  char* ws = (char*)d_ws;
  const size_t MB = 1048576;
  float* stats = (float*)ws;
  float* bqs   = (float*)(ws + 4096);
  bf16* wqkv   = (bf16*)(ws + 8192);
  bf16* wpb    = (bf16*)(ws + 8192 + 393216);
  bf16* xt     = (bf16*)(ws + 1 * MB);
  bf16* Opart  = xt;                                 // alias: xt dead after qkv gemm
  bf16* q      = (bf16*)(ws + 33 * MB);
  bf16* k      = (bf16*)(ws + 41 * MB);
  bf16* v      = (bf16*)(ws + 49 * MB);
  float* lpart = (float*)(ws + 57 * MB);
  bf16* attn   = q;                                  // alias: q dead after flash

  gn_stats_wprep_kernel<<<1152, 256, 0, stream>>>(
      x, stats, wq, wk, wv, wp, bq, bk, bv, wqkv, wpb, bqs);
  gn_prep_kernel<<<dim3(64, 4, NB), 256, 0, stream>>>(x, stats, gn_scale, gn_bias, xt);

  gemm_kernel<<<dim3(128, 6), 256, 0, stream>>>(
      wqkv, xt, bqs, q, k, v, nullptr, nullptr, 0);

  flash_mfma6_kernel<<<dim3(32, NB, 4), 256, 0, stream>>>(q, k, v, Opart, lpart);
  flash_combine4_kernel<<<512, 256, 0, stream>>>(Opart, lpart, attn);

  gemm_kernel<<<dim3(128, 2), 256, 0, stream>>>(
      wpb, attn, bp, nullptr, nullptr, nullptr, out, x, 1);
}